// Round 3
// 167.157 us; speedup vs baseline: 1.0047x; 1.0047x over previous
//
#include <hip/hip_runtime.h>
#include <hip/hip_bf16.h>

// DCNv2 inception, R13b (2nd resubmit; two broker-level infra failures).
// Hedge vs possible source-triggered compile pathology: bb[8] vector array
// replaced with 8 named registers. Semantics identical to R13.
// Theory: offset/mask loads are ALWAYS cold HBM misses (16MB read exactly
// once; FETCH_SIZE confirms), and with prefetch distance 1 issued at loop
// TOP they sit ahead of the B-fragment loads in the in-order vmcnt queue --
// the s_waitcnt releasing the MFMA's B-operands transitively waits out a
// ~900cy HBM miss EVERY tap. Fix:
// (a) param prefetch distance 3 (named ping-pong scalars, no arrays);
// (b) initial 3 taps' params issued BEFORE window staging (latency hides
//     under staging + barrier drain);
// (c) body reordered: B-frag loads issued FIRST (bilinear covers their L2
//     latency), param prefetch issued AFTER them so B's vmcnt wait never
//     covers an outstanding param load. Body else identical to R12.

typedef __attribute__((ext_vector_type(8))) short bf16x8;
typedef __attribute__((ext_vector_type(8))) unsigned short u16x8;
typedef __attribute__((ext_vector_type(4))) float f32x4;
typedef __attribute__((ext_vector_type(2))) float f32x2;

#define WR 16    // window rows
#define WC 30    // window cols
#define WS 68    // window position stride in shorts (34 dwords -> +2 bank rotate)
#define SLS 20   // slab o-stride in floats

__device__ __forceinline__ unsigned short f2bf(float f) {
    __hip_bfloat16 h = __float2bfloat16(f);
    return *reinterpret_cast<unsigned short*>(&h);
}
__device__ __forceinline__ f32x2 unpk(unsigned u) {
    f32x2 r;
    r[0] = __uint_as_float(u << 16);
    r[1] = __uint_as_float(u & 0xffff0000u);
    return r;
}

// Merged prep: blocks [0,256): x[b][c][h][w] f32 -> xTb[b][h][w][c] bf16;
// blocks [256,1584): f[o][c][k] f32 -> wpF in MFMA-fragment order:
//   wpF[k][ct][cg][lane][j] = f[o=ct*16+(lane&15)][c=cg*32+(lane>>4)*8+j][k]
__global__ __launch_bounds__(256) void k_prep(
    const float* __restrict__ x,
    const float* __restrict__ f1, const float* __restrict__ f2, const float* __restrict__ f3,
    unsigned short* __restrict__ xTb,
    unsigned short* __restrict__ wp1, unsigned short* __restrict__ wp2, unsigned short* __restrict__ wp3) {
    __shared__ float tile[64][65];
    int bid = blockIdx.x;
    int tid = threadIdx.x;
    if (bid < 256) {
        int b = bid >> 6, h = bid & 63;
        {
            int w = tid & 63, c4 = tid >> 6;
            const float* xp = x + (((b * 64) * 64 + h) * 64) + w;
            #pragma unroll
            for (int i = 0; i < 16; ++i) {
                int c = c4 * 16 + i;
                tile[c][w] = xp[c * 4096];
            }
        }
        __syncthreads();
        {
            int c = tid & 63, w4 = tid >> 6;
            unsigned short* op = xTb + (((b * 64 + h) * 64) * 64) + c;
            #pragma unroll
            for (int i = 0; i < 16; ++i) {
                int ww = w4 * 16 + i;
                op[ww * 64] = f2bf(tile[c][ww]);
            }
        }
    } else {
        int idx = (bid - 256) * 256 + tid;      // 83*4096 = 339968 total
        const float* f; unsigned short* wp; int K, rel;
        if (idx < 36864)       { f = f1; wp = wp1; K = 9;  rel = idx; }
        else if (idx < 139264) { f = f2; wp = wp2; K = 25; rel = idx - 36864; }
        else                   { f = f3; wp = wp3; K = 49; rel = idx - 139264; }
        int k    = rel >> 12;
        int r2   = rel & 4095;
        int ct   = r2 >> 10;
        int cg   = (r2 >> 9) & 1;
        int lane = (r2 >> 3) & 63;
        int j    = r2 & 7;
        int o = ct * 16 + (lane & 15);
        int c = cg * 32 + (lane >> 4) * 8 + j;
        wp[rel] = f2bf(f[(o * 64 + c) * K + k]);
    }
}

__global__ __launch_bounds__(512, 4) void k_dcn(
    const unsigned short* __restrict__ xTb,
    const float* __restrict__ off1, const float* __restrict__ msk1, const unsigned short* __restrict__ wp1,
    const float* __restrict__ off2, const float* __restrict__ msk2, const unsigned short* __restrict__ wp2,
    const float* __restrict__ off3, const float* __restrict__ msk3, const unsigned short* __restrict__ wp3,
    float* __restrict__ out) {

    __shared__ __align__(16) unsigned char smem[WR * WC * WS * 2];   // 65,280 B
    unsigned short* win = (unsigned short*)smem;
    float* slab = (float*)smem;          // aliased after taps (8*1280*4 = 40,960 B)

    int tile = blockIdx.x;               // 0..1023
    int b  = tile >> 8;
    int h  = (tile >> 2) & 63;
    int w0 = (tile & 3) << 4;

    int tid  = threadIdx.x;
    int wv   = tid >> 6;                 // 0..7
    int lane = tid & 63;
    int quad = lane >> 4;
    int l16  = lane & 15;
    int ylo  = h - 7, cxlo = w0 - 7;

    const unsigned short* xb = xTb + ((size_t)b << 18);

    int pw   = w0 + l16;
    int ch0  = quad << 3;
    int lofs = lane << 3;                // lane*8 shorts = lane*16 B

    // ---- per-wave descriptor (scalar, compact): 8 single tap-ranges ----
    // wv0: br0 k0..9 | wv1: br1 0..12 | wv2: br1 12..25 | wv3..7: br2 in 10s
    const float* offs; const float* msks; const unsigned short* wpF;
    int ks, ke, kw, pad;
    switch (wv) {
        case 0:  offs = off1; msks = msk1; wpF = wp1; kw = 3; pad = 1; ks = 0;  ke = 9;  break;
        case 1:  offs = off2; msks = msk2; wpF = wp2; kw = 5; pad = 2; ks = 0;  ke = 12; break;
        case 2:  offs = off2; msks = msk2; wpF = wp2; kw = 5; pad = 2; ks = 12; ke = 25; break;
        case 3:  offs = off3; msks = msk3; wpF = wp3; kw = 7; pad = 3; ks = 0;  ke = 10; break;
        case 4:  offs = off3; msks = msk3; wpF = wp3; kw = 7; pad = 3; ks = 10; ke = 20; break;
        case 5:  offs = off3; msks = msk3; wpF = wp3; kw = 7; pad = 3; ks = 20; ke = 30; break;
        case 6:  offs = off3; msks = msk3; wpF = wp3; kw = 7; pad = 3; ks = 30; ke = 40; break;
        default: offs = off3; msks = msk3; wpF = wp3; kw = 7; pad = 3; ks = 40; ke = 49; break;
    }
    int K2 = (kw == 3) ? 9 : (kw == 5) ? 25 : 49;
    const float* offp = offs + ((b * 2 * K2) * 4096) + (h << 6) + pw;  // +k*8192 dy, +4096 dx
    const float* mskp = msks + ((b * K2) * 4096) + (h << 6) + pw;      // +k*4096

    // ---- param preload, distance 3: issued BEFORE staging so the cold
    //      HBM latency hides under the staging loop + barrier drain ----
    int kp1 = min(ks + 1, ke - 1), kp2 = min(ks + 2, ke - 1);
    float dyA = offp[ks * 8192], dxA = offp[ks * 8192 + 4096], mkA = mskp[ks * 4096];
    float dyB = offp[kp1 * 8192], dxB = offp[kp1 * 8192 + 4096], mkB = mskp[kp1 * 4096];
    float dyC = offp[kp2 * 8192], dxC = offp[kp2 * 8192 + 4096], mkC = mskp[kp2 * 4096];

    // ---- stage window: 480 positions x 128 B, coalesced, 512 threads ----
    {
        int j = tid & 7;
        for (int p = tid >> 3; p < WR * WC; p += 64) {
            int r = p / WC, cc = p - r * WC;
            int y = min(max(ylo + r, 0), 63);
            int x = min(max(cxlo + cc, 0), 63);
            *(u16x8*)(win + p * WS + j * 8) =
                *(const u16x8*)(xb + (((y << 6) + x) << 6) + j * 8);
        }
    }
    __syncthreads();

    f32x4 acc[4];
    #pragma unroll
    for (int i = 0; i < 4; ++i) acc[i] = (f32x4){0.f, 0.f, 0.f, 0.f};

    int ky = ks / kw, kx = ks - ky * kw;

    for (int k = ks; k < ke; ++k) {
        // B fragments for THIS tap, issued FIRST: bilinear section below
        // (~500cy) covers their L2 latency, and nothing HBM-cold sits
        // ahead of them in the vmcnt queue. Named regs (no array).
        const unsigned short* wpk = wpF + (k << 12) + lofs;
        bf16x8 b00 = *(const bf16x8*)(wpk);
        bf16x8 b01 = *(const bf16x8*)(wpk + 512);
        bf16x8 b10 = *(const bf16x8*)(wpk + 1024);
        bf16x8 b11 = *(const bf16x8*)(wpk + 1536);
        bf16x8 b20 = *(const bf16x8*)(wpk + 2048);
        bf16x8 b21 = *(const bf16x8*)(wpk + 2560);
        bf16x8 b30 = *(const bf16x8*)(wpk + 3072);
        bf16x8 b31 = *(const bf16x8*)(wpk + 3584);

        // param prefetch for tap k+3, issued AFTER the B-frag loads:
        // the wait releasing the B-frags never retires these.
        int kn = min(k + 3, ke - 1);
        float dyN = offp[kn * 8192];
        float dxN = offp[kn * 8192 + 4096];
        float mkN = mskp[kn * 4096];

        float py = (float)(h - pad + ky) + dyA;
        float px = (float)(pw - pad + kx) + dxA;
        float y0f = floorf(py), x0f = floorf(px);
        float wy = py - y0f, wx = px - x0f;
        int y0 = (int)y0f, x0 = (int)x0f;
        int y1 = y0 + 1, x1 = x0 + 1;
        float fy0 = ((unsigned)y0 < 64u) ? (1.f - wy) * mkA : 0.f;
        float fy1 = ((unsigned)y1 < 64u) ? wy * mkA         : 0.f;
        float gx0 = ((unsigned)x0 < 64u) ? (1.f - wx)       : 0.f;
        float gx1 = ((unsigned)x1 < 64u) ? wx               : 0.f;
        float w00 = fy0 * gx0, w01 = fy0 * gx1, w10 = fy1 * gx0, w11 = fy1 * gx1;

        int r0 = y0 - ylo, r1 = r0 + 1;
        int c0 = x0 - cxlo, c1 = c0 + 1;
        bool oow = ((w00 != 0.f) & (((unsigned)r0 >= WR) | ((unsigned)c0 >= WC)))
                 | ((w01 != 0.f) & (((unsigned)r0 >= WR) | ((unsigned)c1 >= WC)))
                 | ((w10 != 0.f) & (((unsigned)r1 >= WR) | ((unsigned)c0 >= WC)))
                 | ((w11 != 0.f) & (((unsigned)r1 >= WR) | ((unsigned)c1 >= WC)));
        int r0c = min(max(r0, 0), WR - 1), r1c = min(max(r1, 0), WR - 1);
        int c0c = min(max(c0, 0), WC - 1), c1c = min(max(c1, 0), WC - 1);
        int p00 = (r0c * WC + c0c) * WS;
        int p01 = (r0c * WC + c1c) * WS;
        int p10 = (r1c * WC + c0c) * WS;
        int p11 = (r1c * WC + c1c) * WS;

        union U { u16x8 v; unsigned u[4]; };
        U g00a, g01a, g10a, g11a, g00b, g01b, g10b, g11b;
        g00a.v = *(const u16x8*)(win + p00 + ch0);
        g01a.v = *(const u16x8*)(win + p01 + ch0);
        g10a.v = *(const u16x8*)(win + p10 + ch0);
        g11a.v = *(const u16x8*)(win + p11 + ch0);
        g00b.v = *(const u16x8*)(win + p00 + 32 + ch0);
        g01b.v = *(const u16x8*)(win + p01 + 32 + ch0);
        g10b.v = *(const u16x8*)(win + p10 + 32 + ch0);
        g11b.v = *(const u16x8*)(win + p11 + 32 + ch0);

        if (oow) {   // valid corner outside window: needs |off|>~4sd, ~never
            int y0g = min(max(y0, 0), 63), y1g = min(max(y1, 0), 63);
            int x0g = min(max(x0, 0), 63), x1g = min(max(x1, 0), 63);
            int o00 = ((y0g << 6) + x0g) << 6;
            int o01 = ((y0g << 6) + x1g) << 6;
            int o10 = ((y1g << 6) + x0g) << 6;
            int o11 = ((y1g << 6) + x1g) << 6;
            g00a.v = *(const u16x8*)(xb + o00 + ch0);
            g01a.v = *(const u16x8*)(xb + o01 + ch0);
            g10a.v = *(const u16x8*)(xb + o10 + ch0);
            g11a.v = *(const u16x8*)(xb + o11 + ch0);
            g00b.v = *(const u16x8*)(xb + o00 + 32 + ch0);
            g01b.v = *(const u16x8*)(xb + o01 + 32 + ch0);
            g10b.v = *(const u16x8*)(xb + o10 + 32 + ch0);
            g11b.v = *(const u16x8*)(xb + o11 + 32 + ch0);
        }

        f32x2 W00 = {w00, w00}, W01 = {w01, w01}, W10 = {w10, w10}, W11 = {w11, w11};
        union { bf16x8 v; unsigned short u[8]; } A0, A1;
        #pragma unroll
        for (int j2 = 0; j2 < 4; ++j2) {
            f32x2 s0 = W00 * unpk(g00a.u[j2]) + W01 * unpk(g01a.u[j2])
                     + W10 * unpk(g10a.u[j2]) + W11 * unpk(g11a.u[j2]);
            f32x2 s1 = W00 * unpk(g00b.u[j2]) + W01 * unpk(g01b.u[j2])
                     + W10 * unpk(g10b.u[j2]) + W11 * unpk(g11b.u[j2]);
            A0.u[2 * j2]     = f2bf(s0[0]);
            A0.u[2 * j2 + 1] = f2bf(s0[1]);
            A1.u[2 * j2]     = f2bf(s1[0]);
            A1.u[2 * j2 + 1] = f2bf(s1[1]);
        }

        acc[0] = __builtin_amdgcn_mfma_f32_16x16x32_bf16(A0.v, b00, acc[0], 0, 0, 0);
        acc[0] = __builtin_amdgcn_mfma_f32_16x16x32_bf16(A1.v, b01, acc[0], 0, 0, 0);
        acc[1] = __builtin_amdgcn_mfma_f32_16x16x32_bf16(A0.v, b10, acc[1], 0, 0, 0);
        acc[1] = __builtin_amdgcn_mfma_f32_16x16x32_bf16(A1.v, b11, acc[1], 0, 0, 0);
        acc[2] = __builtin_amdgcn_mfma_f32_16x16x32_bf16(A0.v, b20, acc[2], 0, 0, 0);
        acc[2] = __builtin_amdgcn_mfma_f32_16x16x32_bf16(A1.v, b21, acc[2], 0, 0, 0);
        acc[3] = __builtin_amdgcn_mfma_f32_16x16x32_bf16(A0.v, b30, acc[3], 0, 0, 0);
        acc[3] = __builtin_amdgcn_mfma_f32_16x16x32_bf16(A1.v, b31, acc[3], 0, 0, 0);

        dyA = dyB; dyB = dyC; dyC = dyN;
        dxA = dxB; dxB = dxC; dxC = dxN;
        mkA = mkB; mkB = mkC; mkC = mkN;
        if (++kx == kw) { kx = 0; ++ky; }
    }

    __syncthreads();    // all waves done reading window; safe to alias as slab

    #pragma unroll
    for (int ct = 0; ct < 4; ++ct) {
        *(f32x4*)&slab[wv * 1280 + (ct * 16 + l16) * SLS + quad * 4] = acc[ct];
    }
    __syncthreads();

    // in-block reduce + store: 768 items = 192 o x 4 groups of 4 px
    // br0 (o<64): slab 0; br1: slabs 1+2; br2: slabs 3..7
    for (int it = tid; it < 768; it += 512) {
        int g = it & 3;
        int o = it >> 2;            // 0..191 (concat order br0|br1|br2)
        int oo = o & 63;
        int base = oo * SLS + g * 4;
        f32x4 v;
        if (o < 64) {
            v = *(const f32x4*)&slab[base];
        } else if (o < 128) {
            f32x4 a0 = *(const f32x4*)&slab[1 * 1280 + base];
            f32x4 a1 = *(const f32x4*)&slab[2 * 1280 + base];
            #pragma unroll
            for (int r = 0; r < 4; ++r) v[r] = a0[r] + a1[r];
        } else {
            f32x4 a0 = *(const f32x4*)&slab[3 * 1280 + base];
            f32x4 a1 = *(const f32x4*)&slab[4 * 1280 + base];
            f32x4 a2 = *(const f32x4*)&slab[5 * 1280 + base];
            f32x4 a3 = *(const f32x4*)&slab[6 * 1280 + base];
            f32x4 a4 = *(const f32x4*)&slab[7 * 1280 + base];
            #pragma unroll
            for (int r = 0; r < 4; ++r) v[r] = (a0[r] + a1[r]) + (a2[r] + a3[r]) + a4[r];
        }
        *(f32x4*)&out[(((size_t)b * 192 + o) * 64 + h) * 64 + w0 + g * 4] = v;
    }
}

extern "C" void kernel_launch(void* const* d_in, const int* in_sizes, int n_in,
                              void* d_out, int out_size, void* d_ws, size_t ws_size,
                              hipStream_t stream) {
    const float* x    = (const float*)d_in[0];
    const float* f1   = (const float*)d_in[1];
    const float* off1 = (const float*)d_in[2];
    const float* msk1 = (const float*)d_in[3];
    const float* f2   = (const float*)d_in[4];
    const float* off2 = (const float*)d_in[5];
    const float* msk2 = (const float*)d_in[6];
    const float* f3   = (const float*)d_in[7];
    const float* off3 = (const float*)d_in[8];
    const float* msk3 = (const float*)d_in[9];
    float* out = (float*)d_out;

    // ws: xTb 2MB bf16 | wpF1/wpF2/wpF3 bf16 (fragment-major)
    unsigned short* xTb = (unsigned short*)d_ws;
    unsigned short* wp1 = xTb + 4 * 64 * 64 * 64;
    unsigned short* wp2 = wp1 + 9 * 4096;
    unsigned short* wp3 = wp2 + 25 * 4096;

    k_prep<<<dim3(1584), dim3(256), 0, stream>>>(x, f1, f2, f3, xTb, wp1, wp2, wp3);
    k_dcn<<<dim3(1024), dim3(512), 0, stream>>>(xTb,
                                                off1, msk1, wp1,
                                                off2, msk2, wp2,
                                                off3, msk3, wp3,
                                                out);
}